// Round 11
// baseline (230.808 us; speedup 1.0000x reference)
//
#include <hip/hip_runtime.h>
#include <math.h>

#define BB 8
#define LL 1900
#define LPAD 1920
#define EE 256
#define HH 8
#define DD 32
#define MTOK (BB*LL)              // 15200
#define SCALE 0.17677669529663687f

typedef __attribute__((ext_vector_type(8))) short bf16x8;
typedef __attribute__((ext_vector_type(4))) short bf16x4;
typedef __attribute__((ext_vector_type(4))) float floatx4;
typedef __attribute__((ext_vector_type(2))) unsigned uintx2;

__device__ inline short f2bf(float f) {
  unsigned u = __builtin_bit_cast(unsigned, f);
  u += 0x7FFF + ((u >> 16) & 1);
  return (short)(u >> 16);
}

// pack 4 fp32 -> 4 bf16 (truncate) via v_perm_b32
__device__ inline bf16x4 pack4(float s0, float s1, float s2, float s3) {
  uintx2 u;
  u.x = __builtin_amdgcn_perm(__builtin_bit_cast(unsigned, s1),
                              __builtin_bit_cast(unsigned, s0), 0x07060302u);
  u.y = __builtin_amdgcn_perm(__builtin_bit_cast(unsigned, s3),
                              __builtin_bit_cast(unsigned, s2), 0x07060302u);
  return __builtin_bit_cast(bf16x4, u);
}

// ---------------- Kernel 0: fp32 -> bf16 for in_proj_w, out_w only --------
#define CVT_W4  49152             // 196608/4
#define CVT_OW4 16384             // 65536/4
#define CVT_TOT (CVT_W4 + CVT_OW4)    // 65536 = 256*256
__global__ __launch_bounds__(256) void cvt_kernel(
    const float* __restrict__ w, const float* __restrict__ ow,
    short* __restrict__ wb, short* __restrict__ owb) {
  int i = blockIdx.x * 256 + threadIdx.x;
  const float* src; short* dst; int off;
  if (i < CVT_W4) { src = w; dst = wb; off = i; }
  else { src = ow; dst = owb; off = i - CVT_W4; }
  float4 v = *(const float4*)(src + (size_t)off * 4);
  short4 o;
  o.x = f2bf(v.x); o.y = f2bf(v.y); o.z = f2bf(v.z); o.w = f2bf(v.w);
  *(short4*)(dst + (size_t)off * 4) = o;
}

// ---------------- Kernel A: QKV projection (LDS-staged x, 4 ntiles/block) -
// block = (mtile, group): stages the 64x256 x-tile once (16 bulk float4
// loads/thread -> high memory concurrency), then 128 MFMAs/wave from LDS
// against L2-hot w. grid 720 = 3 groups x 240 mtiles; 240%8==0 keeps all
// blocks of one mtile on one XCD.
#define XSTR 264   // x-tile LDS row stride in shorts (528 B, 16B-aligned)
__global__ __launch_bounds__(256) void qkv_kernel(
    const float* __restrict__ x, const short* __restrict__ w,
    const float* __restrict__ bias, short* __restrict__ q,
    short* __restrict__ k, short* __restrict__ vt) {
  __shared__ short xbuf[64 * XSTR];   // 33.8 KB; epilogue cbuf aliases it
  int bid = blockIdx.x;
  int mtile = bid % 240, group = bid / 240;   // group: 0=q 1=k 2=v
  if (mtile >= 238) return;
  int wv = threadIdx.x >> 6, lane = threadIdx.x & 63;
  int l15 = lane & 15, quad = lane >> 4;

  // ---- stage x tile (64 rows x 256 fp32) -> bf16 LDS ----
  {
    int srow = threadIdx.x & 63;
    int scol = (threadIdx.x >> 6) * 64;
    int stok = mtile * 64 + srow;
    if (stok >= MTOK) stok = MTOK - 1;
    const float* xr = x + (size_t)stok * EE + scol;
#pragma unroll
    for (int i = 0; i < 8; ++i) {
      float4 a0 = *(const float4*)(xr + i * 8);
      float4 a1 = *(const float4*)(xr + i * 8 + 4);
      bf16x8 bv;
      bv[0] = f2bf(a0.x); bv[1] = f2bf(a0.y); bv[2] = f2bf(a0.z); bv[3] = f2bf(a0.w);
      bv[4] = f2bf(a1.x); bv[5] = f2bf(a1.y); bv[6] = f2bf(a1.z); bv[7] = f2bf(a1.w);
      *(bf16x8*)&xbuf[srow * XSTR + scol + i * 8] = bv;
    }
  }
  __syncthreads();

  // ---- main loop: acc[nt][ns], A-frags from LDS, B-frags from global ----
  floatx4 acc[4][4];
#pragma unroll
  for (int nt = 0; nt < 4; ++nt)
#pragma unroll
    for (int ns = 0; ns < 4; ++ns) acc[nt][ns] = (floatx4){0.f, 0.f, 0.f, 0.f};

#pragma unroll
  for (int ks = 0; ks < 8; ++ks) {
    bf16x8 af = *(bf16x8*)&xbuf[(wv * 16 + l15) * XSTR + ks * 32 + quad * 8];
#pragma unroll
    for (int nt = 0; nt < 4; ++nt)
#pragma unroll
      for (int ns = 0; ns < 4; ++ns) {
        int frow = (group * 4 + nt) * 64 + ns * 16 + l15;
        bf16x8 bfr = *(const bf16x8*)(w + (size_t)frow * EE + ks * 32 + quad * 8);
        acc[nt][ns] = __builtin_amdgcn_mfma_f32_16x16x32_bf16(af, bfr, acc[nt][ns], 0, 0, 0);
      }
  }
  __syncthreads();   // retire all xbuf reads before cbuf reuse

  // ---- epilogue per ntile: bias(+scale), LDS transpose, vector stores ----
  short* cbuf = xbuf;   // 64*72 shorts, aliases xbuf
  float qs = (group == 0) ? SCALE : 1.0f;
  int t0tok = mtile * 64;
  int b0 = t0tok / LL;
  bool uni = (b0 == (t0tok + 63) / LL) && (t0tok + 63 < MTOK);

  for (int nt = 0; nt < 4; ++nt) {
    int ntile = group * 4 + nt;
#pragma unroll
    for (int ns = 0; ns < 4; ++ns) {
      float bv = bias[ntile * 64 + ns * 16 + l15];
#pragma unroll
      for (int r = 0; r < 4; ++r)
        cbuf[(wv * 16 + quad * 4 + r) * 72 + ns * 16 + l15] = f2bf((acc[nt][ns][r] + bv) * qs);
    }
    __syncthreads();

    int fbase = nt * 64;
    if (group < 2) {
      short* dst0 = group ? k : q;
      int tl = threadIdx.x >> 2, seg = threadIdx.x & 3;
      int tok = t0tok + tl;
      if (tok < MTOK) {
        int b = uni ? b0 : tok / LL;
        int l = tok - b * LL;
        int fl = seg * 16;
        int h = (fbase + fl) >> 5;
        int d = (fbase + fl) & 31;
        size_t base = ((size_t)(b * HH + h) * LPAD + l) * DD + d;
        bf16x8 v0 = *(bf16x8*)(&cbuf[tl * 72 + fl]);
        bf16x8 v1 = *(bf16x8*)(&cbuf[tl * 72 + fl + 8]);
        *(bf16x8*)(dst0 + base) = v0;
        *(bf16x8*)(dst0 + base + 8) = v1;
      }
    } else {
      int fl = threadIdx.x >> 2, ls = threadIdx.x & 3;
      int h = (fbase + fl) >> 5;
      int d = (fbase + fl) & 31;
      if (uni) {
        int l0 = t0tok - b0 * LL + ls * 16;
        size_t base = ((size_t)(b0 * HH + h) * DD + d) * LPAD + l0;
#pragma unroll
        for (int g4 = 0; g4 < 4; ++g4) {
          int tb = ls * 16 + g4 * 4;
          short4 vv;
          vv.x = cbuf[(tb + 0) * 72 + fl];
          vv.y = cbuf[(tb + 1) * 72 + fl];
          vv.z = cbuf[(tb + 2) * 72 + fl];
          vv.w = cbuf[(tb + 3) * 72 + fl];
          *(short4*)(vt + base + g4 * 4) = vv;
        }
      } else {
#pragma unroll
        for (int i = 0; i < 16; ++i) {
          int tl = ls * 16 + i;
          int tok = t0tok + tl;
          if (tok < MTOK) {
            int b = tok / LL;
            int l = tok - b * LL;
            vt[((size_t)(b * HH + h) * DD + d) * LPAD + l] = cbuf[tl * 72 + fl];
          }
        }
      }
    }
    __syncthreads();   // WAR: next nt rewrites cbuf
  }
}

// ---------------- Kernel B: flash attention, LDS-staged band --------------
// S^T = K*Q^T via one mfma_16x16x32 (A=K b128 frag, B=Q b128 frag). C/D m
// index (quad*4+reg) matches the 16x16x16 PV B-operand k index, so exp(S^T)
// feeds register-only into O^T = V^T * P^T. The always-visible key band
// [t0*64, 1920) is staged chunk-wise into LDS by the whole block and shared
// by all 4 waves (128 q-rows); group tiles (<20%) read global directly.
#define VSTR 260   // vbuf stride (520 B: 8B-aligned b64 reads, bank-clean)
__global__ __launch_bounds__(256) void attn_kernel(
    const short* __restrict__ q, const short* __restrict__ k,
    const short* __restrict__ vt, short* __restrict__ ctx,
    const int* __restrict__ pad_size_p, const int* __restrict__ single_pad_p) {
  __shared__ short kbuf[256 * 40];    // [key][d], stride 40 shorts (80 B)
  __shared__ short vbuf[32 * VSTR];   // [d][key]
  int bid = blockIdx.x;
  int bh = bid & 63, rg = bid >> 6;  // bh fastest -> 8 heads/XCD (L2 fit)
  int wv = threadIdx.x >> 6, lane = threadIdx.x & 63;
  int l15 = lane & 15, quad = lane >> 4;

  int ps = pad_size_p[0];
  int sp2 = 2 * single_pad_p[0];
  int t0 = ps >> 6;                  // 15
  int kb0 = t0 * 64;                 // 960

  const short* Q = q + (size_t)bh * LPAD * DD;
  const short* K = k + (size_t)bh * LPAD * DD;
  const short* VT = vt + (size_t)bh * DD * LPAD;

  int row0 = rg * 128 + wv * 32;

  // Q as B-operand frags (16x16x32): qrow = row0+f*16+l15, dims quad*8..+7
  bf16x8 qf[2];
  qf[0] = *(const bf16x8*)(Q + (size_t)(row0 + l15) * DD + quad * 8);
  qf[1] = *(const bf16x8*)(Q + (size_t)(row0 + 16 + l15) * DD + quad * 8);

  // per-lane (qrow) visible-group window; empty for out-dn rows
  int glo[2], ghi[2];
#pragma unroll
  for (int f = 0; f < 2; ++f) {
    int row = row0 + f * 16 + l15;
    int g = row / sp2;
    int lo = g * sp2, hi = lo + sp2;
    if (row >= ps) { lo = 0; hi = 0; }
    glo[f] = lo; ghi[f] = hi;
  }

  float li[2] = {0.f, 0.f};
  floatx4 ot[2][2];                  // [frag][dblk]
#pragma unroll
  for (int f = 0; f < 2; ++f)
#pragma unroll
    for (int db = 0; db < 2; ++db) ot[f][db] = (floatx4){0.f, 0.f, 0.f, 0.f};

  // ---- group phase: keys < kb0, direct global loads -----------------------
  if (row0 < ps) {
    int rmaxd = row0 + 31;
    if (rmaxd >= ps) rmaxd = ps - 1;
    int c0 = (row0 / sp2) * sp2;
    int c1 = (rmaxd / sp2) * sp2 + sp2;
    if (c1 > ps) c1 = ps;
    int g_t0 = c0 >> 6;
    int g_end = (c1 + 63) >> 6;
    if (g_end > t0) g_end = t0;
    for (int jb = g_t0; jb < g_end; ++jb) {
      int kbase = jb * 64;
      bf16x4 va[2][4];
#pragma unroll
      for (int db = 0; db < 2; ++db)
#pragma unroll
        for (int ns = 0; ns < 4; ++ns)
          va[db][ns] = *(const bf16x4*)(VT + (size_t)(db * 16 + l15) * LPAD + kbase + ns * 16 + quad * 4);
      bf16x4 pt[2][4];
#pragma unroll
      for (int ns = 0; ns < 4; ++ns) {
        bf16x8 ka = *(const bf16x8*)(K + (size_t)(kbase + ns * 16 + l15) * DD + quad * 8);
#pragma unroll
        for (int f = 0; f < 2; ++f) {
          floatx4 z = {0.f, 0.f, 0.f, 0.f};
          floatx4 st = __builtin_amdgcn_mfma_f32_16x16x32_bf16(ka, qf[f], z, 0, 0, 0);
          float e[4];
#pragma unroll
          for (int r = 0; r < 4; ++r) {
            int key = kbase + ns * 16 + quad * 4 + r;
            int vis = (key >= glo[f]) & (key < ghi[f]);
            float ev = vis ? __expf(st[r]) : 0.f;
            li[f] += ev;
            e[r] = ev;
          }
          pt[f][ns] = pack4(e[0], e[1], e[2], e[3]);
        }
      }
#pragma unroll
      for (int f = 0; f < 2; ++f)
#pragma unroll
        for (int db = 0; db < 2; ++db)
#pragma unroll
          for (int ns = 0; ns < 4; ++ns)
            ot[f][db] = __builtin_amdgcn_mfma_f32_16x16x16bf16_1k(va[db][ns], pt[f][ns], ot[f][db], 0, 0, 0);
    }
  }

  // ---- band phase: keys [kb0, LPAD), staged chunk-wise into LDS -----------
  for (int kbase = kb0; kbase < LPAD; kbase += 256) {
    int nk = LPAD - kbase; if (nk > 256) nk = 256;
    // stage K: nk rows x 32 d, four 8-short segments per row
    for (int t = threadIdx.x; t < nk * 4; t += 256) {
      int key = t >> 2, seg = t & 3;
      *(bf16x8*)&kbuf[key * 40 + seg * 8] =
          *(const bf16x8*)(K + (size_t)(kbase + key) * DD + seg * 8);
    }
    // stage V^T: 32 d x nk keys, 8-key segments
    for (int t = threadIdx.x; t < 1024; t += 256) {
      int d = t >> 5, s = t & 31;
      if (s * 8 < nk)
        *(bf16x8*)&vbuf[d * VSTR + s * 8] =
            *(const bf16x8*)(VT + (size_t)d * LPAD + kbase + s * 8);
    }
    __syncthreads();
    int ntiles = nk >> 6;
    for (int t = 0; t < ntiles; ++t) {
      int tk0 = kbase + t * 64;
      bool masked = (tk0 < ps) | (tk0 + 64 > LL);   // group-edge OR tail
      int tl = t * 64;
      bf16x4 va[2][4];
#pragma unroll
      for (int db = 0; db < 2; ++db)
#pragma unroll
        for (int ns = 0; ns < 4; ++ns)
          va[db][ns] = *(const bf16x4*)&vbuf[(db * 16 + l15) * VSTR + tl + ns * 16 + quad * 4];
      bf16x4 pt[2][4];
#pragma unroll
      for (int ns = 0; ns < 4; ++ns) {
        bf16x8 ka = *(const bf16x8*)&kbuf[(tl + ns * 16 + l15) * 40 + quad * 8];
#pragma unroll
        for (int f = 0; f < 2; ++f) {
          floatx4 z = {0.f, 0.f, 0.f, 0.f};
          floatx4 st = __builtin_amdgcn_mfma_f32_16x16x32_bf16(ka, qf[f], z, 0, 0, 0);
          float e[4];
#pragma unroll
          for (int r = 0; r < 4; ++r) {
            float ev = __expf(st[r]);
            if (masked) {
              int key = tk0 + ns * 16 + quad * 4 + r;
              int vis = (key < LL) & ((key >= ps) | ((key >= glo[f]) & (key < ghi[f])));
              ev = vis ? ev : 0.f;
            }
            li[f] += ev;
            e[r] = ev;
          }
          pt[f][ns] = pack4(e[0], e[1], e[2], e[3]);
        }
      }
#pragma unroll
      for (int f = 0; f < 2; ++f)
#pragma unroll
        for (int db = 0; db < 2; ++db)
#pragma unroll
          for (int ns = 0; ns < 4; ++ns)
            ot[f][db] = __builtin_amdgcn_mfma_f32_16x16x16bf16_1k(va[db][ns], pt[f][ns], ot[f][db], 0, 0, 0);
    }
    __syncthreads();
  }

  // denominator: reduce per-lane partials over the 4 quads
#pragma unroll
  for (int f = 0; f < 2; ++f) {
    li[f] += __shfl_xor(li[f], 16);
    li[f] += __shfl_xor(li[f], 32);
  }

  int b = bh >> 3, h = bh & 7;
#pragma unroll
  for (int f = 0; f < 2; ++f) {
    int row = row0 + f * 16 + l15;
    if (row >= LL) continue;
    float inv = 1.f / li[f];
    size_t base = ((size_t)b * LL + row) * EE + h * DD;
#pragma unroll
    for (int db = 0; db < 2; ++db) {
      short4 o;
      o.x = f2bf(ot[f][db][0] * inv);
      o.y = f2bf(ot[f][db][1] * inv);
      o.z = f2bf(ot[f][db][2] * inv);
      o.w = f2bf(ot[f][db][3] * inv);
      *(short4*)(ctx + base + db * 16 + quad * 4) = o;
    }
  }
}

// ---------------- Kernel C: out proj + bias + residual + LayerNorm --------
__global__ __launch_bounds__(256) void outln_kernel(
    const short* __restrict__ ctx, const short* __restrict__ ow,
    const float* __restrict__ ob, const float* __restrict__ x,
    const float* __restrict__ lg, const float* __restrict__ lb,
    float* __restrict__ out) {
  __shared__ float red[4][16][2];
  int mtile = blockIdx.x;               // 0..949, 16 rows each (exact)
  int wv = threadIdx.x >> 6, lane = threadIdx.x & 63;
  int l15 = lane & 15, quad = lane >> 4;
  int rowbase = mtile * 16;

  const short* crow = ctx + (size_t)(rowbase + l15) * EE;

  floatx4 acc[4];
#pragma unroll
  for (int i = 0; i < 4; ++i) acc[i] = (floatx4){0.f, 0.f, 0.f, 0.f};

#pragma unroll
  for (int ks = 0; ks < 8; ++ks) {
    bf16x8 af = *(const bf16x8*)(crow + ks * 32 + quad * 8);
#pragma unroll
    for (int ns = 0; ns < 4; ++ns) {
      int frow = wv * 64 + ns * 16 + l15;
      bf16x8 bfr = *(const bf16x8*)(ow + (size_t)frow * EE + ks * 32 + quad * 8);
      acc[ns] = __builtin_amdgcn_mfma_f32_16x16x32_bf16(af, bfr, acc[ns], 0, 0, 0);
    }
  }

  float obv[4], lgv[4], lbv[4];
#pragma unroll
  for (int ns = 0; ns < 4; ++ns) {
    int c = wv * 64 + ns * 16 + l15;
    obv[ns] = ob[c]; lgv[ns] = lg[c]; lbv[ns] = lb[c];
  }

  float y[4][4];                         // [ns][r]
  float s1[4] = {0.f, 0.f, 0.f, 0.f}, s2[4] = {0.f, 0.f, 0.f, 0.f};
#pragma unroll
  for (int r = 0; r < 4; ++r) {
    int tok = rowbase + quad * 4 + r;
#pragma unroll
    for (int ns = 0; ns < 4; ++ns) {
      int c = wv * 64 + ns * 16 + l15;
      float yy = acc[ns][r] + obv[ns] + x[(size_t)tok * EE + c];
      y[ns][r] = yy;
      s1[r] += yy;
      s2[r] += yy * yy;
    }
  }
#pragma unroll
  for (int r = 0; r < 4; ++r) {
#pragma unroll
    for (int off = 1; off < 16; off <<= 1) {
      s1[r] += __shfl_xor(s1[r], off, 16);
      s2[r] += __shfl_xor(s2[r], off, 16);
    }
  }
  if (l15 == 0) {
#pragma unroll
    for (int r = 0; r < 4; ++r) {
      red[wv][quad * 4 + r][0] = s1[r];
      red[wv][quad * 4 + r][1] = s2[r];
    }
  }
  __syncthreads();
#pragma unroll
  for (int r = 0; r < 4; ++r) {
    int rr = quad * 4 + r;
    float t1 = 0.f, t2 = 0.f;
#pragma unroll
    for (int w2 = 0; w2 < 4; ++w2) { t1 += red[w2][rr][0]; t2 += red[w2][rr][1]; }
    float mu = t1 * (1.f / 256.f);
    float var = t2 * (1.f / 256.f) - mu * mu;
    float rs = rsqrtf(var + 1e-5f);
    int tok = rowbase + rr;
#pragma unroll
    for (int ns = 0; ns < 4; ++ns) {
      int c = wv * 64 + ns * 16 + l15;
      out[(size_t)tok * EE + c] = (y[ns][r] - mu) * rs * lgv[ns] + lbv[ns];
    }
  }
}

extern "C" void kernel_launch(void* const* d_in, const int* in_sizes, int n_in,
                              void* d_out, int out_size, void* d_ws, size_t ws_size,
                              hipStream_t stream) {
  const float* x  = (const float*)d_in[0];
  const float* w  = (const float*)d_in[1];
  const float* wb = (const float*)d_in[2];
  const float* ow = (const float*)d_in[3];
  const float* ob = (const float*)d_in[4];
  const float* lg = (const float*)d_in[5];
  const float* lb = (const float*)d_in[6];
  const int* ps = (const int*)d_in[8];   // pad_size
  const int* sp = (const int*)d_in[9];   // single_pad

  short* wbb = (short*)d_ws;                       // 768*256 bf16
  short* owb = wbb + (size_t)768 * EE;             // 256*256 bf16
  short* qw  = owb + (size_t)256 * EE;             // 64*1920*32 bf16 (pre-scaled)
  short* kw  = qw + (size_t)64 * LPAD * DD;
  short* vtw = kw + (size_t)64 * LPAD * DD;
  short* ctx = vtw + (size_t)64 * LPAD * DD;       // 15200*256 bf16

  cvt_kernel<<<CVT_TOT / 256, 256, 0, stream>>>(w, ow, wbb, owb);
  qkv_kernel<<<720, 256, 0, stream>>>(x, wbb, wb, qw, kw, vtw);
  attn_kernel<<<15 * 64, 256, 0, stream>>>(qw, kw, vtw, ctx, ps, sp);
  outln_kernel<<<950, 256, 0, stream>>>(ctx, owb, ob, x, lg, lb, (float*)d_out);
}

// Round 12
// 222.805 us; speedup vs baseline: 1.0359x; 1.0359x over previous
//
#include <hip/hip_runtime.h>
#include <math.h>

#define BB 8
#define LL 1900
#define LPAD 1920
#define EE 256
#define HH 8
#define DD 32
#define MTOK (BB*LL)              // 15200
#define SCALE 0.17677669529663687f

typedef __attribute__((ext_vector_type(8))) short bf16x8;
typedef __attribute__((ext_vector_type(4))) short bf16x4;
typedef __attribute__((ext_vector_type(4))) float floatx4;
typedef __attribute__((ext_vector_type(2))) unsigned uintx2;

__device__ inline short f2bf(float f) {
  unsigned u = __builtin_bit_cast(unsigned, f);
  u += 0x7FFF + ((u >> 16) & 1);
  return (short)(u >> 16);
}

// pack 4 fp32 -> 4 bf16 (truncate) via v_perm_b32
__device__ inline bf16x4 pack4(float s0, float s1, float s2, float s3) {
  uintx2 u;
  u.x = __builtin_amdgcn_perm(__builtin_bit_cast(unsigned, s1),
                              __builtin_bit_cast(unsigned, s0), 0x07060302u);
  u.y = __builtin_amdgcn_perm(__builtin_bit_cast(unsigned, s3),
                              __builtin_bit_cast(unsigned, s2), 0x07060302u);
  return __builtin_bit_cast(bf16x4, u);
}

// ---------------- Kernel 0: fp32 -> bf16 for in_proj_w, out_w only --------
#define CVT_W4  49152             // 196608/4
#define CVT_OW4 16384             // 65536/4
#define CVT_TOT (CVT_W4 + CVT_OW4)    // 65536 = 256*256
__global__ __launch_bounds__(256) void cvt_kernel(
    const float* __restrict__ w, const float* __restrict__ ow,
    short* __restrict__ wb, short* __restrict__ owb) {
  int i = blockIdx.x * 256 + threadIdx.x;
  const float* src; short* dst; int off;
  if (i < CVT_W4) { src = w; dst = wb; off = i; }
  else { src = ow; dst = owb; off = i - CVT_W4; }
  float4 v = *(const float4*)(src + (size_t)off * 4);
  short4 o;
  o.x = f2bf(v.x); o.y = f2bf(v.y); o.z = f2bf(v.z); o.w = f2bf(v.w);
  *(short4*)(dst + (size_t)off * 4) = o;
}

// ---------------- Kernel A: QKV projection (hoisted bulk loads) -----------
// R10 grid (240x12, XCD-affine mtile) + ALL 48 loads (16 x-float4 + 32
// w-bf16x8) issued before any compute: ~48 loads in flight per wave covers
// the L2-cold ~900cyc latency (ws re-poison evicts L2 before every launch).
__global__ __launch_bounds__(256) void qkv_kernel(
    const float* __restrict__ x, const short* __restrict__ w,
    const float* __restrict__ bias, short* __restrict__ q,
    short* __restrict__ k, short* __restrict__ vt) {
  __shared__ short cbuf[64 * 72];
  int bid = blockIdx.x;
  int mtile = bid % 240, ntile = bid / 240;
  if (mtile >= 238) return;
  int wv = threadIdx.x >> 6, lane = threadIdx.x & 63;
  int l15 = lane & 15, quad = lane >> 4;

  int arow = mtile * 64 + wv * 16 + l15;
  if (arow >= MTOK) arow = MTOK - 1;
  const float* xrow = x + (size_t)arow * EE;

  // ---- bulk load phase: everything in flight at once ----
  float4 xa[8][2];
#pragma unroll
  for (int ks = 0; ks < 8; ++ks) {
    xa[ks][0] = *(const float4*)(xrow + ks * 32 + quad * 8);
    xa[ks][1] = *(const float4*)(xrow + ks * 32 + quad * 8 + 4);
  }
  bf16x8 wr[8][4];
#pragma unroll
  for (int ks = 0; ks < 8; ++ks)
#pragma unroll
    for (int ns = 0; ns < 4; ++ns) {
      int frow = ntile * 64 + ns * 16 + l15;
      wr[ks][ns] = *(const bf16x8*)(w + (size_t)frow * EE + ks * 32 + quad * 8);
    }
  asm volatile("" ::: "memory");   // pin loads above compute

  // ---- compute phase ----
  floatx4 acc[4];
#pragma unroll
  for (int i = 0; i < 4; ++i) acc[i] = (floatx4){0.f, 0.f, 0.f, 0.f};
#pragma unroll
  for (int ks = 0; ks < 8; ++ks) {
    float4 a0 = xa[ks][0], a1 = xa[ks][1];
    bf16x8 af;
    af[0] = f2bf(a0.x); af[1] = f2bf(a0.y); af[2] = f2bf(a0.z); af[3] = f2bf(a0.w);
    af[4] = f2bf(a1.x); af[5] = f2bf(a1.y); af[6] = f2bf(a1.z); af[7] = f2bf(a1.w);
#pragma unroll
    for (int ns = 0; ns < 4; ++ns)
      acc[ns] = __builtin_amdgcn_mfma_f32_16x16x32_bf16(af, wr[ks][ns], acc[ns], 0, 0, 0);
  }

  // ---- epilogue: bias(+scale), LDS transpose, vector stores (as R10) ----
  float qs = (ntile < 4) ? SCALE : 1.0f;
#pragma unroll
  for (int ns = 0; ns < 4; ++ns) {
    float bv = bias[ntile * 64 + ns * 16 + l15];
#pragma unroll
    for (int r = 0; r < 4; ++r)
      cbuf[(wv * 16 + quad * 4 + r) * 72 + ns * 16 + l15] = f2bf((acc[ns][r] + bv) * qs);
  }
  __syncthreads();

  int t0tok = mtile * 64;
  int b0 = t0tok / LL;
  bool uni = (b0 == (t0tok + 63) / LL) && (t0tok + 63 < MTOK);
  int which = ntile >> 2;          // 0=q 1=k 2=v
  int fbase = (ntile & 3) * 64;

  if (which < 2) {
    short* dst0 = which ? k : q;
    int tl = threadIdx.x >> 2, seg = threadIdx.x & 3;
    int tok = t0tok + tl;
    if (tok < MTOK) {
      int b = uni ? b0 : tok / LL;
      int l = tok - b * LL;
      int fl = seg * 16;
      int h = (fbase + fl) >> 5;
      int d = (fbase + fl) & 31;
      size_t base = ((size_t)(b * HH + h) * LPAD + l) * DD + d;
      bf16x8 v0 = *(bf16x8*)(&cbuf[tl * 72 + fl]);
      bf16x8 v1 = *(bf16x8*)(&cbuf[tl * 72 + fl + 8]);
      *(bf16x8*)(dst0 + base) = v0;
      *(bf16x8*)(dst0 + base + 8) = v1;
    }
  } else {
    int fl = threadIdx.x >> 2, ls = threadIdx.x & 3;
    int h = (fbase + fl) >> 5;
    int d = (fbase + fl) & 31;
    if (uni) {
      int l0 = t0tok - b0 * LL + ls * 16;
      size_t base = ((size_t)(b0 * HH + h) * DD + d) * LPAD + l0;
#pragma unroll
      for (int g4 = 0; g4 < 4; ++g4) {
        int tb = ls * 16 + g4 * 4;
        short4 vv;
        vv.x = cbuf[(tb + 0) * 72 + fl];
        vv.y = cbuf[(tb + 1) * 72 + fl];
        vv.z = cbuf[(tb + 2) * 72 + fl];
        vv.w = cbuf[(tb + 3) * 72 + fl];
        *(short4*)(vt + base + g4 * 4) = vv;
      }
    } else {
#pragma unroll
      for (int i = 0; i < 16; ++i) {
        int tl = ls * 16 + i;
        int tok = t0tok + tl;
        if (tok < MTOK) {
          int b = tok / LL;
          int l = tok - b * LL;
          vt[((size_t)(b * HH + h) * DD + d) * LPAD + l] = cbuf[tl * 72 + fl];
        }
      }
    }
  }
}

// ---------------- Kernel B: flash attention, LDS-staged band --------------
#define VSTR 260   // vbuf stride (520 B: 8B-aligned b64 reads, bank-clean)
__global__ __launch_bounds__(256) void attn_kernel(
    const short* __restrict__ q, const short* __restrict__ k,
    const short* __restrict__ vt, short* __restrict__ ctx,
    const int* __restrict__ pad_size_p, const int* __restrict__ single_pad_p) {
  __shared__ short kbuf[256 * 40];    // [key][d], stride 40 shorts (80 B)
  __shared__ short vbuf[32 * VSTR];   // [d][key]
  int bid = blockIdx.x;
  int bh = bid & 63, rg = bid >> 6;  // bh fastest -> 8 heads/XCD (L2 fit)
  int wv = threadIdx.x >> 6, lane = threadIdx.x & 63;
  int l15 = lane & 15, quad = lane >> 4;

  int ps = pad_size_p[0];
  int sp2 = 2 * single_pad_p[0];
  int t0 = ps >> 6;                  // 15
  int kb0 = t0 * 64;                 // 960

  const short* Q = q + (size_t)bh * LPAD * DD;
  const short* K = k + (size_t)bh * LPAD * DD;
  const short* VT = vt + (size_t)bh * DD * LPAD;

  int row0 = rg * 128 + wv * 32;

  bf16x8 qf[2];
  qf[0] = *(const bf16x8*)(Q + (size_t)(row0 + l15) * DD + quad * 8);
  qf[1] = *(const bf16x8*)(Q + (size_t)(row0 + 16 + l15) * DD + quad * 8);

  int glo[2], ghi[2];
#pragma unroll
  for (int f = 0; f < 2; ++f) {
    int row = row0 + f * 16 + l15;
    int g = row / sp2;
    int lo = g * sp2, hi = lo + sp2;
    if (row >= ps) { lo = 0; hi = 0; }
    glo[f] = lo; ghi[f] = hi;
  }

  float li[2] = {0.f, 0.f};
  floatx4 ot[2][2];
#pragma unroll
  for (int f = 0; f < 2; ++f)
#pragma unroll
    for (int db = 0; db < 2; ++db) ot[f][db] = (floatx4){0.f, 0.f, 0.f, 0.f};

  // ---- group phase: keys < kb0, direct global loads ----
  if (row0 < ps) {
    int rmaxd = row0 + 31;
    if (rmaxd >= ps) rmaxd = ps - 1;
    int c0 = (row0 / sp2) * sp2;
    int c1 = (rmaxd / sp2) * sp2 + sp2;
    if (c1 > ps) c1 = ps;
    int g_t0 = c0 >> 6;
    int g_end = (c1 + 63) >> 6;
    if (g_end > t0) g_end = t0;
    for (int jb = g_t0; jb < g_end; ++jb) {
      int kbase = jb * 64;
      bf16x4 va[2][4];
#pragma unroll
      for (int db = 0; db < 2; ++db)
#pragma unroll
        for (int ns = 0; ns < 4; ++ns)
          va[db][ns] = *(const bf16x4*)(VT + (size_t)(db * 16 + l15) * LPAD + kbase + ns * 16 + quad * 4);
      bf16x4 pt[2][4];
#pragma unroll
      for (int ns = 0; ns < 4; ++ns) {
        bf16x8 ka = *(const bf16x8*)(K + (size_t)(kbase + ns * 16 + l15) * DD + quad * 8);
#pragma unroll
        for (int f = 0; f < 2; ++f) {
          floatx4 z = {0.f, 0.f, 0.f, 0.f};
          floatx4 st = __builtin_amdgcn_mfma_f32_16x16x32_bf16(ka, qf[f], z, 0, 0, 0);
          float e[4];
#pragma unroll
          for (int r = 0; r < 4; ++r) {
            int key = kbase + ns * 16 + quad * 4 + r;
            int vis = (key >= glo[f]) & (key < ghi[f]);
            float ev = vis ? __expf(st[r]) : 0.f;
            li[f] += ev;
            e[r] = ev;
          }
          pt[f][ns] = pack4(e[0], e[1], e[2], e[3]);
        }
      }
#pragma unroll
      for (int f = 0; f < 2; ++f)
#pragma unroll
        for (int db = 0; db < 2; ++db)
#pragma unroll
          for (int ns = 0; ns < 4; ++ns)
            ot[f][db] = __builtin_amdgcn_mfma_f32_16x16x16bf16_1k(va[db][ns], pt[f][ns], ot[f][db], 0, 0, 0);
    }
  }

  // ---- band phase: keys [kb0, LPAD), staged chunk-wise into LDS ----
  for (int kbase = kb0; kbase < LPAD; kbase += 256) {
    int nk = LPAD - kbase; if (nk > 256) nk = 256;
    for (int t = threadIdx.x; t < nk * 4; t += 256) {
      int key = t >> 2, seg = t & 3;
      *(bf16x8*)&kbuf[key * 40 + seg * 8] =
          *(const bf16x8*)(K + (size_t)(kbase + key) * DD + seg * 8);
    }
    for (int t = threadIdx.x; t < 1024; t += 256) {
      int d = t >> 5, s = t & 31;
      if (s * 8 < nk)
        *(bf16x8*)&vbuf[d * VSTR + s * 8] =
            *(const bf16x8*)(VT + (size_t)d * LPAD + kbase + s * 8);
    }
    __syncthreads();
    int ntiles = nk >> 6;
    for (int t = 0; t < ntiles; ++t) {
      int tk0 = kbase + t * 64;
      bool masked = (tk0 < ps) | (tk0 + 64 > LL);   // group-edge OR tail
      int tl = t * 64;
      bf16x4 va[2][4];
#pragma unroll
      for (int db = 0; db < 2; ++db)
#pragma unroll
        for (int ns = 0; ns < 4; ++ns)
          va[db][ns] = *(const bf16x4*)&vbuf[(db * 16 + l15) * VSTR + tl + ns * 16 + quad * 4];
      bf16x4 pt[2][4];
#pragma unroll
      for (int ns = 0; ns < 4; ++ns) {
        bf16x8 ka = *(const bf16x8*)&kbuf[(tl + ns * 16 + l15) * 40 + quad * 8];
#pragma unroll
        for (int f = 0; f < 2; ++f) {
          floatx4 z = {0.f, 0.f, 0.f, 0.f};
          floatx4 st = __builtin_amdgcn_mfma_f32_16x16x32_bf16(ka, qf[f], z, 0, 0, 0);
          float e[4];
#pragma unroll
          for (int r = 0; r < 4; ++r) {
            float ev = __expf(st[r]);
            if (masked) {
              int key = tk0 + ns * 16 + quad * 4 + r;
              int vis = (key < LL) & ((key >= ps) | ((key >= glo[f]) & (key < ghi[f])));
              ev = vis ? ev : 0.f;
            }
            li[f] += ev;
            e[r] = ev;
          }
          pt[f][ns] = pack4(e[0], e[1], e[2], e[3]);
        }
      }
#pragma unroll
      for (int f = 0; f < 2; ++f)
#pragma unroll
        for (int db = 0; db < 2; ++db)
#pragma unroll
          for (int ns = 0; ns < 4; ++ns)
            ot[f][db] = __builtin_amdgcn_mfma_f32_16x16x16bf16_1k(va[db][ns], pt[f][ns], ot[f][db], 0, 0, 0);
    }
    __syncthreads();
  }

#pragma unroll
  for (int f = 0; f < 2; ++f) {
    li[f] += __shfl_xor(li[f], 16);
    li[f] += __shfl_xor(li[f], 32);
  }

  int b = bh >> 3, h = bh & 7;
#pragma unroll
  for (int f = 0; f < 2; ++f) {
    int row = row0 + f * 16 + l15;
    if (row >= LL) continue;
    float inv = 1.f / li[f];
    size_t base = ((size_t)b * LL + row) * EE + h * DD;
#pragma unroll
    for (int db = 0; db < 2; ++db) {
      short4 o;
      o.x = f2bf(ot[f][db][0] * inv);
      o.y = f2bf(ot[f][db][1] * inv);
      o.z = f2bf(ot[f][db][2] * inv);
      o.w = f2bf(ot[f][db][3] * inv);
      *(short4*)(ctx + base + db * 16 + quad * 4) = o;
    }
  }
}

// ---------------- Kernel C: out proj + residual + LayerNorm (hoisted) -----
#define OXS 260
__global__ __launch_bounds__(256) void outln_kernel(
    const short* __restrict__ ctx, const short* __restrict__ ow,
    const float* __restrict__ ob, const float* __restrict__ x,
    const float* __restrict__ lg, const float* __restrict__ lb,
    float* __restrict__ out) {
  __shared__ float xs[16 * OXS];        // residual x tile (coalesced staging)
  __shared__ float red[4][16][2];
  int mtile = blockIdx.x;               // 0..949, 16 rows each (exact)
  int wv = threadIdx.x >> 6, lane = threadIdx.x & 63;
  int l15 = lane & 15, quad = lane >> 4;
  int rowbase = mtile * 16;

  // ---- bulk load phase: x-stage + ctx + ow all in flight ----
  float4 xv[4];
#pragma unroll
  for (int i = 0; i < 4; ++i) {
    int row = (threadIdx.x >> 6) + i * 4;
    int col = (threadIdx.x & 63) * 4;
    xv[i] = *(const float4*)(x + (size_t)(rowbase + row) * EE + col);
  }
  const short* crow = ctx + (size_t)(rowbase + l15) * EE;
  bf16x8 ca[8];
#pragma unroll
  for (int ks = 0; ks < 8; ++ks)
    ca[ks] = *(const bf16x8*)(crow + ks * 32 + quad * 8);
  bf16x8 wr[8][4];
#pragma unroll
  for (int ks = 0; ks < 8; ++ks)
#pragma unroll
    for (int ns = 0; ns < 4; ++ns) {
      int frow = wv * 64 + ns * 16 + l15;
      wr[ks][ns] = *(const bf16x8*)(ow + (size_t)frow * EE + ks * 32 + quad * 8);
    }
  asm volatile("" ::: "memory");

#pragma unroll
  for (int i = 0; i < 4; ++i) {
    int row = (threadIdx.x >> 6) + i * 4;
    int col = (threadIdx.x & 63) * 4;
    *(float4*)&xs[row * OXS + col] = xv[i];
  }
  __syncthreads();

  floatx4 acc[4];
#pragma unroll
  for (int i = 0; i < 4; ++i) acc[i] = (floatx4){0.f, 0.f, 0.f, 0.f};
#pragma unroll
  for (int ks = 0; ks < 8; ++ks)
#pragma unroll
    for (int ns = 0; ns < 4; ++ns)
      acc[ns] = __builtin_amdgcn_mfma_f32_16x16x32_bf16(ca[ks], wr[ks][ns], acc[ns], 0, 0, 0);

  float obv[4], lgv[4], lbv[4];
#pragma unroll
  for (int ns = 0; ns < 4; ++ns) {
    int c = wv * 64 + ns * 16 + l15;
    obv[ns] = ob[c]; lgv[ns] = lg[c]; lbv[ns] = lb[c];
  }

  float y[4][4];                         // [ns][r]
  float s1[4] = {0.f, 0.f, 0.f, 0.f}, s2[4] = {0.f, 0.f, 0.f, 0.f};
#pragma unroll
  for (int r = 0; r < 4; ++r) {
    int rr = quad * 4 + r;
#pragma unroll
    for (int ns = 0; ns < 4; ++ns) {
      int c = wv * 64 + ns * 16 + l15;
      float yy = acc[ns][r] + obv[ns] + xs[rr * OXS + c];
      y[ns][r] = yy;
      s1[r] += yy;
      s2[r] += yy * yy;
    }
  }
#pragma unroll
  for (int r = 0; r < 4; ++r) {
#pragma unroll
    for (int off = 1; off < 16; off <<= 1) {
      s1[r] += __shfl_xor(s1[r], off, 16);
      s2[r] += __shfl_xor(s2[r], off, 16);
    }
  }
  if (l15 == 0) {
#pragma unroll
    for (int r = 0; r < 4; ++r) {
      red[wv][quad * 4 + r][0] = s1[r];
      red[wv][quad * 4 + r][1] = s2[r];
    }
  }
  __syncthreads();
#pragma unroll
  for (int r = 0; r < 4; ++r) {
    int rr = quad * 4 + r;
    float t1 = 0.f, t2 = 0.f;
#pragma unroll
    for (int w2 = 0; w2 < 4; ++w2) { t1 += red[w2][rr][0]; t2 += red[w2][rr][1]; }
    float mu = t1 * (1.f / 256.f);
    float var = t2 * (1.f / 256.f) - mu * mu;
    float rs = rsqrtf(var + 1e-5f);
    int tok = rowbase + rr;
#pragma unroll
    for (int ns = 0; ns < 4; ++ns) {
      int c = wv * 64 + ns * 16 + l15;
      out[(size_t)tok * EE + c] = (y[ns][r] - mu) * rs * lgv[ns] + lbv[ns];
    }
  }
}

extern "C" void kernel_launch(void* const* d_in, const int* in_sizes, int n_in,
                              void* d_out, int out_size, void* d_ws, size_t ws_size,
                              hipStream_t stream) {
  const float* x  = (const float*)d_in[0];
  const float* w  = (const float*)d_in[1];
  const float* wb = (const float*)d_in[2];
  const float* ow = (const float*)d_in[3];
  const float* ob = (const float*)d_in[4];
  const float* lg = (const float*)d_in[5];
  const float* lb = (const float*)d_in[6];
  const int* ps = (const int*)d_in[8];   // pad_size
  const int* sp = (const int*)d_in[9];   // single_pad

  short* wbb = (short*)d_ws;                       // 768*256 bf16
  short* owb = wbb + (size_t)768 * EE;             // 256*256 bf16
  short* qw  = owb + (size_t)256 * EE;             // 64*1920*32 bf16 (pre-scaled)
  short* kw  = qw + (size_t)64 * LPAD * DD;
  short* vtw = kw + (size_t)64 * LPAD * DD;
  short* ctx = vtw + (size_t)64 * LPAD * DD;       // 15200*256 bf16

  cvt_kernel<<<CVT_TOT / 256, 256, 0, stream>>>(w, ow, wbb, owb);
  qkv_kernel<<<240 * 12, 256, 0, stream>>>(x, wbb, wb, qw, kw, vtw);
  attn_kernel<<<15 * 64, 256, 0, stream>>>(qw, kw, vtw, ctx, ps, sp);
  outln_kernel<<<950, 256, 0, stream>>>(ctx, owb, ob, x, lg, lb, (float*)d_out);
}

// Round 13
// 209.864 us; speedup vs baseline: 1.0998x; 1.0617x over previous
//
#include <hip/hip_runtime.h>
#include <math.h>

#define BB 8
#define LL 1900
#define LPAD 1920
#define EE 256
#define HH 8
#define DD 32
#define MTOK (BB*LL)              // 15200
#define SCALE 0.17677669529663687f

typedef __attribute__((ext_vector_type(8))) short bf16x8;
typedef __attribute__((ext_vector_type(4))) short bf16x4;
typedef __attribute__((ext_vector_type(4))) float floatx4;
typedef __attribute__((ext_vector_type(2))) unsigned uintx2;

__device__ inline short f2bf(float f) {
  unsigned u = __builtin_bit_cast(unsigned, f);
  u += 0x7FFF + ((u >> 16) & 1);
  return (short)(u >> 16);
}

// pack 4 fp32 -> 4 bf16 (truncate) via v_perm_b32
__device__ inline bf16x4 pack4(float s0, float s1, float s2, float s3) {
  uintx2 u;
  u.x = __builtin_amdgcn_perm(__builtin_bit_cast(unsigned, s1),
                              __builtin_bit_cast(unsigned, s0), 0x07060302u);
  u.y = __builtin_amdgcn_perm(__builtin_bit_cast(unsigned, s3),
                              __builtin_bit_cast(unsigned, s2), 0x07060302u);
  return __builtin_bit_cast(bf16x4, u);
}

// async global->LDS DMA, 16 B per lane; lds base must be wave-uniform
__device__ inline void load_lds16(const void* g, void* l) {
  __builtin_amdgcn_global_load_lds(
      (const __attribute__((address_space(1))) unsigned*)g,
      (__attribute__((address_space(3))) unsigned*)l, 16, 0, 0);
}

// ---------------- Kernel 0: fp32 -> bf16 for in_proj_w, out_w only --------
#define CVT_W4  49152             // 196608/4
#define CVT_OW4 16384             // 65536/4
#define CVT_TOT (CVT_W4 + CVT_OW4)    // 65536 = 256*256
__global__ __launch_bounds__(256) void cvt_kernel(
    const float* __restrict__ w, const float* __restrict__ ow,
    short* __restrict__ wb, short* __restrict__ owb) {
  int i = blockIdx.x * 256 + threadIdx.x;
  const float* src; short* dst; int off;
  if (i < CVT_W4) { src = w; dst = wb; off = i; }
  else { src = ow; dst = owb; off = i - CVT_W4; }
  float4 v = *(const float4*)(src + (size_t)off * 4);
  short4 o;
  o.x = f2bf(v.x); o.y = f2bf(v.y); o.z = f2bf(v.z); o.w = f2bf(v.w);
  *(short4*)(dst + (size_t)off * 4) = o;
}

// ---------------- Kernel A: QKV projection (DMA-staged x) -----------------
// Each wave DMAs its 16 x-rows (fp32) into a wave-private LDS slice via
// global_load_lds (no VGPR cost -> 16 KB in flight per wave, ~137 KB/CU),
// waits vmcnt(0) once, then computes from LDS with in-register bf16 cvt.
// Grid 240x12, mtile fastest (240%8==0 -> XCD-affine x reuse in L2).
#define XF 268    // x LDS row stride in floats (1072 B: 16B-aligned, even banks)
__global__ __launch_bounds__(256) void qkv_kernel(
    const float* __restrict__ x, const short* __restrict__ w,
    const float* __restrict__ bias, short* __restrict__ q,
    short* __restrict__ k, short* __restrict__ vt) {
  __shared__ float xs[4 * 16 * XF];   // 68.6 KB; epilogue cbuf aliases it
  int bid = blockIdx.x;
  int mtile = bid % 240, ntile = bid / 240;
  if (mtile >= 238) return;
  int wv = threadIdx.x >> 6, lane = threadIdx.x & 63;
  int l15 = lane & 15, quad = lane >> 4;

  float* xw = &xs[wv * 16 * XF];      // wave-private slice

  // ---- DMA phase: 16 rows x 1 KB per wave, all in flight ----
#pragma unroll
  for (int i = 0; i < 16; ++i) {
    int row = mtile * 64 + wv * 16 + i;
    if (row >= MTOK) row = MTOK - 1;
    load_lds16(x + (size_t)row * EE + lane * 4, xw + i * XF);
  }
  asm volatile("s_waitcnt vmcnt(0)" ::: "memory");

  // ---- compute phase: A-frags from LDS (fp32 -> bf16), B from L2-warm w --
  floatx4 acc[4];
#pragma unroll
  for (int i = 0; i < 4; ++i) acc[i] = (floatx4){0.f, 0.f, 0.f, 0.f};
#pragma unroll
  for (int ks = 0; ks < 8; ++ks) {
    float4 a0 = *(const float4*)&xw[l15 * XF + ks * 32 + quad * 8];
    float4 a1 = *(const float4*)&xw[l15 * XF + ks * 32 + quad * 8 + 4];
    bf16x8 af;
    af[0] = f2bf(a0.x); af[1] = f2bf(a0.y); af[2] = f2bf(a0.z); af[3] = f2bf(a0.w);
    af[4] = f2bf(a1.x); af[5] = f2bf(a1.y); af[6] = f2bf(a1.z); af[7] = f2bf(a1.w);
#pragma unroll
    for (int ns = 0; ns < 4; ++ns) {
      int frow = ntile * 64 + ns * 16 + l15;
      bf16x8 bfr = *(const bf16x8*)(w + (size_t)frow * EE + ks * 32 + quad * 8);
      acc[ns] = __builtin_amdgcn_mfma_f32_16x16x32_bf16(af, bfr, acc[ns], 0, 0, 0);
    }
  }
  __syncthreads();   // all waves done reading xs before cbuf overwrites it

  // ---- epilogue: bias(+scale), LDS transpose, vector stores ----
  short* cbuf = (short*)xs;          // 64*72 shorts, aliases xs
  float qs = (ntile < 4) ? SCALE : 1.0f;
#pragma unroll
  for (int ns = 0; ns < 4; ++ns) {
    float bv = bias[ntile * 64 + ns * 16 + l15];
#pragma unroll
    for (int r = 0; r < 4; ++r)
      cbuf[(wv * 16 + quad * 4 + r) * 72 + ns * 16 + l15] = f2bf((acc[ns][r] + bv) * qs);
  }
  __syncthreads();

  int t0tok = mtile * 64;
  int b0 = t0tok / LL;
  bool uni = (b0 == (t0tok + 63) / LL) && (t0tok + 63 < MTOK);
  int which = ntile >> 2;          // 0=q 1=k 2=v
  int fbase = (ntile & 3) * 64;

  if (which < 2) {
    short* dst0 = which ? k : q;
    int tl = threadIdx.x >> 2, seg = threadIdx.x & 3;
    int tok = t0tok + tl;
    if (tok < MTOK) {
      int b = uni ? b0 : tok / LL;
      int l = tok - b * LL;
      int fl = seg * 16;
      int h = (fbase + fl) >> 5;
      int d = (fbase + fl) & 31;
      size_t base = ((size_t)(b * HH + h) * LPAD + l) * DD + d;
      bf16x8 v0 = *(bf16x8*)(&cbuf[tl * 72 + fl]);
      bf16x8 v1 = *(bf16x8*)(&cbuf[tl * 72 + fl + 8]);
      *(bf16x8*)(dst0 + base) = v0;
      *(bf16x8*)(dst0 + base + 8) = v1;
    }
  } else {
    int fl = threadIdx.x >> 2, ls = threadIdx.x & 3;
    int h = (fbase + fl) >> 5;
    int d = (fbase + fl) & 31;
    if (uni) {
      int l0 = t0tok - b0 * LL + ls * 16;
      size_t base = ((size_t)(b0 * HH + h) * DD + d) * LPAD + l0;
#pragma unroll
      for (int g4 = 0; g4 < 4; ++g4) {
        int tb = ls * 16 + g4 * 4;
        short4 vv;
        vv.x = cbuf[(tb + 0) * 72 + fl];
        vv.y = cbuf[(tb + 1) * 72 + fl];
        vv.z = cbuf[(tb + 2) * 72 + fl];
        vv.w = cbuf[(tb + 3) * 72 + fl];
        *(short4*)(vt + base + g4 * 4) = vv;
      }
    } else {
#pragma unroll
      for (int i = 0; i < 16; ++i) {
        int tl = ls * 16 + i;
        int tok = t0tok + tl;
        if (tok < MTOK) {
          int b = tok / LL;
          int l = tok - b * LL;
          vt[((size_t)(b * HH + h) * DD + d) * LPAD + l] = cbuf[tl * 72 + fl];
        }
      }
    }
  }
}

// ---------------- Kernel B: flash attention, LDS-staged band --------------
#define VSTR 260   // vbuf stride (520 B: 8B-aligned b64 reads, bank-clean)
__global__ __launch_bounds__(256) void attn_kernel(
    const short* __restrict__ q, const short* __restrict__ k,
    const short* __restrict__ vt, short* __restrict__ ctx,
    const int* __restrict__ pad_size_p, const int* __restrict__ single_pad_p) {
  __shared__ short kbuf[256 * 40];    // [key][d], stride 40 shorts (80 B)
  __shared__ short vbuf[32 * VSTR];   // [d][key]
  int bid = blockIdx.x;
  int bh = bid & 63, rg = bid >> 6;  // bh fastest -> 8 heads/XCD (L2 fit)
  int wv = threadIdx.x >> 6, lane = threadIdx.x & 63;
  int l15 = lane & 15, quad = lane >> 4;

  int ps = pad_size_p[0];
  int sp2 = 2 * single_pad_p[0];
  int t0 = ps >> 6;                  // 15
  int kb0 = t0 * 64;                 // 960

  const short* Q = q + (size_t)bh * LPAD * DD;
  const short* K = k + (size_t)bh * LPAD * DD;
  const short* VT = vt + (size_t)bh * DD * LPAD;

  int row0 = rg * 128 + wv * 32;

  bf16x8 qf[2];
  qf[0] = *(const bf16x8*)(Q + (size_t)(row0 + l15) * DD + quad * 8);
  qf[1] = *(const bf16x8*)(Q + (size_t)(row0 + 16 + l15) * DD + quad * 8);

  int glo[2], ghi[2];
#pragma unroll
  for (int f = 0; f < 2; ++f) {
    int row = row0 + f * 16 + l15;
    int g = row / sp2;
    int lo = g * sp2, hi = lo + sp2;
    if (row >= ps) { lo = 0; hi = 0; }
    glo[f] = lo; ghi[f] = hi;
  }

  float li[2] = {0.f, 0.f};
  floatx4 ot[2][2];
#pragma unroll
  for (int f = 0; f < 2; ++f)
#pragma unroll
    for (int db = 0; db < 2; ++db) ot[f][db] = (floatx4){0.f, 0.f, 0.f, 0.f};

  // ---- group phase: keys < kb0, direct global loads ----
  if (row0 < ps) {
    int rmaxd = row0 + 31;
    if (rmaxd >= ps) rmaxd = ps - 1;
    int c0 = (row0 / sp2) * sp2;
    int c1 = (rmaxd / sp2) * sp2 + sp2;
    if (c1 > ps) c1 = ps;
    int g_t0 = c0 >> 6;
    int g_end = (c1 + 63) >> 6;
    if (g_end > t0) g_end = t0;
    for (int jb = g_t0; jb < g_end; ++jb) {
      int kbase = jb * 64;
      bf16x4 va[2][4];
#pragma unroll
      for (int db = 0; db < 2; ++db)
#pragma unroll
        for (int ns = 0; ns < 4; ++ns)
          va[db][ns] = *(const bf16x4*)(VT + (size_t)(db * 16 + l15) * LPAD + kbase + ns * 16 + quad * 4);
      bf16x4 pt[2][4];
#pragma unroll
      for (int ns = 0; ns < 4; ++ns) {
        bf16x8 ka = *(const bf16x8*)(K + (size_t)(kbase + ns * 16 + l15) * DD + quad * 8);
#pragma unroll
        for (int f = 0; f < 2; ++f) {
          floatx4 z = {0.f, 0.f, 0.f, 0.f};
          floatx4 st = __builtin_amdgcn_mfma_f32_16x16x32_bf16(ka, qf[f], z, 0, 0, 0);
          float e[4];
#pragma unroll
          for (int r = 0; r < 4; ++r) {
            int key = kbase + ns * 16 + quad * 4 + r;
            int vis = (key >= glo[f]) & (key < ghi[f]);
            float ev = vis ? __expf(st[r]) : 0.f;
            li[f] += ev;
            e[r] = ev;
          }
          pt[f][ns] = pack4(e[0], e[1], e[2], e[3]);
        }
      }
#pragma unroll
      for (int f = 0; f < 2; ++f)
#pragma unroll
        for (int db = 0; db < 2; ++db)
#pragma unroll
          for (int ns = 0; ns < 4; ++ns)
            ot[f][db] = __builtin_amdgcn_mfma_f32_16x16x16bf16_1k(va[db][ns], pt[f][ns], ot[f][db], 0, 0, 0);
    }
  }

  // ---- band phase: keys [kb0, LPAD), staged chunk-wise into LDS ----
  for (int kbase = kb0; kbase < LPAD; kbase += 256) {
    int nk = LPAD - kbase; if (nk > 256) nk = 256;
    for (int t = threadIdx.x; t < nk * 4; t += 256) {
      int key = t >> 2, seg = t & 3;
      *(bf16x8*)&kbuf[key * 40 + seg * 8] =
          *(const bf16x8*)(K + (size_t)(kbase + key) * DD + seg * 8);
    }
    for (int t = threadIdx.x; t < 1024; t += 256) {
      int d = t >> 5, s = t & 31;
      if (s * 8 < nk)
        *(bf16x8*)&vbuf[d * VSTR + s * 8] =
            *(const bf16x8*)(VT + (size_t)d * LPAD + kbase + s * 8);
    }
    __syncthreads();
    int ntiles = nk >> 6;
    for (int t = 0; t < ntiles; ++t) {
      int tk0 = kbase + t * 64;
      bool masked = (tk0 < ps) | (tk0 + 64 > LL);   // group-edge OR tail
      int tl = t * 64;
      bf16x4 va[2][4];
#pragma unroll
      for (int db = 0; db < 2; ++db)
#pragma unroll
        for (int ns = 0; ns < 4; ++ns)
          va[db][ns] = *(const bf16x4*)&vbuf[(db * 16 + l15) * VSTR + tl + ns * 16 + quad * 4];
      bf16x4 pt[2][4];
#pragma unroll
      for (int ns = 0; ns < 4; ++ns) {
        bf16x8 ka = *(const bf16x8*)&kbuf[(tl + ns * 16 + l15) * 40 + quad * 8];
#pragma unroll
        for (int f = 0; f < 2; ++f) {
          floatx4 z = {0.f, 0.f, 0.f, 0.f};
          floatx4 st = __builtin_amdgcn_mfma_f32_16x16x32_bf16(ka, qf[f], z, 0, 0, 0);
          float e[4];
#pragma unroll
          for (int r = 0; r < 4; ++r) {
            float ev = __expf(st[r]);
            if (masked) {
              int key = tk0 + ns * 16 + quad * 4 + r;
              int vis = (key < LL) & ((key >= ps) | ((key >= glo[f]) & (key < ghi[f])));
              ev = vis ? ev : 0.f;
            }
            li[f] += ev;
            e[r] = ev;
          }
          pt[f][ns] = pack4(e[0], e[1], e[2], e[3]);
        }
      }
#pragma unroll
      for (int f = 0; f < 2; ++f)
#pragma unroll
        for (int db = 0; db < 2; ++db)
#pragma unroll
          for (int ns = 0; ns < 4; ++ns)
            ot[f][db] = __builtin_amdgcn_mfma_f32_16x16x16bf16_1k(va[db][ns], pt[f][ns], ot[f][db], 0, 0, 0);
    }
    __syncthreads();
  }

#pragma unroll
  for (int f = 0; f < 2; ++f) {
    li[f] += __shfl_xor(li[f], 16);
    li[f] += __shfl_xor(li[f], 32);
  }

  int b = bh >> 3, h = bh & 7;
#pragma unroll
  for (int f = 0; f < 2; ++f) {
    int row = row0 + f * 16 + l15;
    if (row >= LL) continue;
    float inv = 1.f / li[f];
    size_t base = ((size_t)b * LL + row) * EE + h * DD;
#pragma unroll
    for (int db = 0; db < 2; ++db) {
      short4 o;
      o.x = f2bf(ot[f][db][0] * inv);
      o.y = f2bf(ot[f][db][1] * inv);
      o.z = f2bf(ot[f][db][2] * inv);
      o.w = f2bf(ot[f][db][3] * inv);
      *(short4*)(ctx + base + db * 16 + quad * 4) = o;
    }
  }
}

// ---------------- Kernel C: out proj + residual + LayerNorm ---------------
#define OXS 260
__global__ __launch_bounds__(256) void outln_kernel(
    const short* __restrict__ ctx, const short* __restrict__ ow,
    const float* __restrict__ ob, const float* __restrict__ x,
    const float* __restrict__ lg, const float* __restrict__ lb,
    float* __restrict__ out) {
  __shared__ float xs[16 * OXS];        // residual x tile (coalesced staging)
  __shared__ float red[4][16][2];
  int mtile = blockIdx.x;               // 0..949, 16 rows each (exact)
  int wv = threadIdx.x >> 6, lane = threadIdx.x & 63;
  int l15 = lane & 15, quad = lane >> 4;
  int rowbase = mtile * 16;

  float4 xv[4];
#pragma unroll
  for (int i = 0; i < 4; ++i) {
    int row = (threadIdx.x >> 6) + i * 4;
    int col = (threadIdx.x & 63) * 4;
    xv[i] = *(const float4*)(x + (size_t)(rowbase + row) * EE + col);
  }
  const short* crow = ctx + (size_t)(rowbase + l15) * EE;
  bf16x8 ca[8];
#pragma unroll
  for (int ks = 0; ks < 8; ++ks)
    ca[ks] = *(const bf16x8*)(crow + ks * 32 + quad * 8);
  bf16x8 wr[8][4];
#pragma unroll
  for (int ks = 0; ks < 8; ++ks)
#pragma unroll
    for (int ns = 0; ns < 4; ++ns) {
      int frow = wv * 64 + ns * 16 + l15;
      wr[ks][ns] = *(const bf16x8*)(ow + (size_t)frow * EE + ks * 32 + quad * 8);
    }
  asm volatile("" ::: "memory");

#pragma unroll
  for (int i = 0; i < 4; ++i) {
    int row = (threadIdx.x >> 6) + i * 4;
    int col = (threadIdx.x & 63) * 4;
    *(float4*)&xs[row * OXS + col] = xv[i];
  }
  __syncthreads();

  floatx4 acc[4];
#pragma unroll
  for (int i = 0; i < 4; ++i) acc[i] = (floatx4){0.f, 0.f, 0.f, 0.f};
#pragma unroll
  for (int ks = 0; ks < 8; ++ks)
#pragma unroll
    for (int ns = 0; ns < 4; ++ns)
      acc[ns] = __builtin_amdgcn_mfma_f32_16x16x32_bf16(ca[ks], wr[ks][ns], acc[ns], 0, 0, 0);

  float obv[4], lgv[4], lbv[4];
#pragma unroll
  for (int ns = 0; ns < 4; ++ns) {
    int c = wv * 64 + ns * 16 + l15;
    obv[ns] = ob[c]; lgv[ns] = lg[c]; lbv[ns] = lb[c];
  }

  float y[4][4];                         // [ns][r]
  float s1[4] = {0.f, 0.f, 0.f, 0.f}, s2[4] = {0.f, 0.f, 0.f, 0.f};
#pragma unroll
  for (int r = 0; r < 4; ++r) {
    int rr = quad * 4 + r;
#pragma unroll
    for (int ns = 0; ns < 4; ++ns) {
      int c = wv * 64 + ns * 16 + l15;
      float yy = acc[ns][r] + obv[ns] + xs[rr * OXS + c];
      y[ns][r] = yy;
      s1[r] += yy;
      s2[r] += yy * yy;
    }
  }
#pragma unroll
  for (int r = 0; r < 4; ++r) {
#pragma unroll
    for (int off = 1; off < 16; off <<= 1) {
      s1[r] += __shfl_xor(s1[r], off, 16);
      s2[r] += __shfl_xor(s2[r], off, 16);
    }
  }
  if (l15 == 0) {
#pragma unroll
    for (int r = 0; r < 4; ++r) {
      red[wv][quad * 4 + r][0] = s1[r];
      red[wv][quad * 4 + r][1] = s2[r];
    }
  }
  __syncthreads();
#pragma unroll
  for (int r = 0; r < 4; ++r) {
    int rr = quad * 4 + r;
    float t1 = 0.f, t2 = 0.f;
#pragma unroll
    for (int w2 = 0; w2 < 4; ++w2) { t1 += red[w2][rr][0]; t2 += red[w2][rr][1]; }
    float mu = t1 * (1.f / 256.f);
    float var = t2 * (1.f / 256.f) - mu * mu;
    float rs = rsqrtf(var + 1e-5f);
    int tok = rowbase + rr;
#pragma unroll
    for (int ns = 0; ns < 4; ++ns) {
      int c = wv * 64 + ns * 16 + l15;
      out[(size_t)tok * EE + c] = (y[ns][r] - mu) * rs * lgv[ns] + lbv[ns];
    }
  }
}

extern "C" void kernel_launch(void* const* d_in, const int* in_sizes, int n_in,
                              void* d_out, int out_size, void* d_ws, size_t ws_size,
                              hipStream_t stream) {
  const float* x  = (const float*)d_in[0];
  const float* w  = (const float*)d_in[1];
  const float* wb = (const float*)d_in[2];
  const float* ow = (const float*)d_in[3];
  const float* ob = (const float*)d_in[4];
  const float* lg = (const float*)d_in[5];
  const float* lb = (const float*)d_in[6];
  const int* ps = (const int*)d_in[8];   // pad_size
  const int* sp = (const int*)d_in[9];   // single_pad

  short* wbb = (short*)d_ws;                       // 768*256 bf16
  short* owb = wbb + (size_t)768 * EE;             // 256*256 bf16
  short* qw  = owb + (size_t)256 * EE;             // 64*1920*32 bf16 (pre-scaled)
  short* kw  = qw + (size_t)64 * LPAD * DD;
  short* vtw = kw + (size_t)64 * LPAD * DD;
  short* ctx = vtw + (size_t)64 * LPAD * DD;       // 15200*256 bf16

  cvt_kernel<<<CVT_TOT / 256, 256, 0, stream>>>(w, ow, wbb, owb);
  qkv_kernel<<<240 * 12, 256, 0, stream>>>(x, wbb, wb, qw, kw, vtw);
  attn_kernel<<<15 * 64, 256, 0, stream>>>(qw, kw, vtw, ctx, ps, sp);
  outln_kernel<<<950, 256, 0, stream>>>(ctx, owb, ob, x, lg, lb, (float*)d_out);
}